// Round 5
// baseline (854.795 us; speedup 1.0000x reference)
//
#include <hip/hip_runtime.h>
#include <hip/hip_bf16.h>

#define N_PTS 8192
#define LATENT 64

typedef __attribute__((ext_vector_type(8))) short short8;
typedef __attribute__((ext_vector_type(4))) float f32x4;

#define MFMA16(a, b, c) __builtin_amdgcn_mfma_f32_16x16x32_bf16(a, b, c, 0, 0, 0)

__device__ __forceinline__ unsigned short f2bf_rne(float f) {
    unsigned u = __float_as_uint(f);
    u += 0x7fff + ((u >> 16) & 1);
    return (unsigned short)(u >> 16);
}
__device__ __forceinline__ float bf2f(unsigned short h) {
    return __uint_as_float(((unsigned)h) << 16);
}
__device__ __forceinline__ unsigned pack_hi16(unsigned lo, unsigned hi) {
    return __builtin_amdgcn_perm(hi, lo, 0x07060302);
}
__device__ __forceinline__ unsigned rne_hi(unsigned u) {
    return u + 0x7fff + ((u >> 16) & 1);
}

// k-dimension permutation (kappa): activation for output-index o of the
// previous layer is stored at k-position kappa(o).
__device__ __forceinline__ int kappa(int o) {
    int j  = (((o >> 3) & 1) << 2) | ((o >> 4) & 3);
    int qk = (o >> 1) & 3;
    int kc = ((o >> 6) << 1) | (o & 1);
    return (kc << 5) | (qk << 3) | j;
}

// ---------------------------------------------------------------------------
// Kernel 1: gate GEMV + top-k -> compact (idx,val) lists AND dense gate matrix
// ---------------------------------------------------------------------------
struct GateParams {
    const float* latents;
    const float* gw[5];
    const float* gb[5];
    int*   idx_out;   // [5][64][256]
    float* val_out;   // [5][64][256]
    float* gdense;    // [5][64][1024], zero-padded to 1024
    int E[5];
    int K[5];
};

__global__ __launch_bounds__(256) void gate_topk(GateParams P) {
    const int n = blockIdx.x, l = blockIdx.y, t = threadIdx.x;
    const int E = P.E[l], K = P.K[l];
    __shared__ float lat[LATENT];
    __shared__ float gv[1024];
    __shared__ float ga[1024];
    __shared__ int s_cntgt, s_pos;

    if (t < LATENT) lat[t] = P.latents[(n * 5 + l) * LATENT + t];
    if (t == 0) { s_cntgt = 0; s_pos = 0; }
    __syncthreads();

    const float* gwl = P.gw[l];
    const float* gbl = P.gb[l];
    for (int e = t; e < E; e += 256) {
        float acc = gbl[e];
        const float* row = gwl + e * LATENT;
        #pragma unroll 8
        for (int j = 0; j < LATENT; ++j) acc = fmaf(lat[j], row[j], acc);
        gv[e] = acc;
        ga[e] = fabsf(acc);
    }

    for (int size = 2; size <= E; size <<= 1) {
        for (int stride = size >> 1; stride > 0; stride >>= 1) {
            __syncthreads();
            for (int i = t; i < E; i += 256) {
                int j = i ^ stride;
                if (j > i) {
                    float a = ga[i], b = ga[j];
                    bool up = ((i & size) == 0);
                    if ((a > b) == up) { ga[i] = b; ga[j] = a; }
                }
            }
        }
    }
    __syncthreads();
    const float thr = ga[E - K];

    for (int e = t; e < E; e += 256)
        if (fabsf(gv[e]) > thr) atomicAdd(&s_cntgt, 1);
    __syncthreads();
    const int needed = K - s_cntgt;

    float* gd = P.gdense + ((size_t)l * 64 + n) * 1024;
    for (int e = t; e < 1024; e += 256) {
        float outv = 0.f;
        if (e < E) {
            float a = fabsf(gv[e]);
            bool keep = (a > thr);
            if (!keep && a == thr) {
                int r = 0;
                for (int e2 = 0; e2 < e; ++e2)
                    if (fabsf(gv[e2]) == thr) ++r;
                keep = (r < needed);
            }
            if (keep) {
                int pos = atomicAdd(&s_pos, 1);
                P.idx_out[(l * 64 + n) * 256 + pos] = e;
                P.val_out[(l * 64 + n) * 256 + pos] = gv[e];
                outv = gv[e];
            }
        }
        gd[e] = outv;
    }
}

// ---------------------------------------------------------------------------
// Kernel 2: ALL combines in one launch.
//  blocks [0,64)    : layer-0 W fragment bank (W0F)          (compact lists)
//  blocks [64,832)  : layers 1-3 DENSE-GEMM combine: block = (layer, o-row),
//                     thread = k, 64 fp32 accs (one per instance). Each w row
//                     is read exactly once across the whole grid.
//  blocks [832,896) : layer-4 B-frag combine (compact, K=256)
// ---------------------------------------------------------------------------
struct CombParams {
    const float *w0, *b0, *w1, *b1, *w2, *b2, *w3, *b3, *w4, *b4;
    const int* idxl; const float* vall;
    const float* gdense;
    unsigned short* W0F;
    unsigned short *Bh1, *Bl1, *Bh2, *Bl2, *Bh3, *Bl3, *Bh4, *Bl4;
    float *bc1, *bc2, *bc3, *bc4;
};

__global__ __launch_bounds__(256) void combine_all(CombParams C) {
    const int b = blockIdx.x;
    const int t = threadIdx.x;
    __shared__ int   sidx[256];
    __shared__ float sval[256];
    __shared__ float Gs[64][64];   // dense gate chunk [n][ee]

    if (b < 64) {
        // ---- layer-0 fragment bank ----
        const int n = b;
        if (t < 4) { sidx[t] = C.idxl[n * 256 + t]; sval[t] = C.vall[n * 256 + t]; }
        __syncthreads();
        const int o = t;
        float wx = 0.f, wy = 0.f, bb = 0.f;
        #pragma unroll
        for (int e = 0; e < 4; ++e) {
            const float g = sval[e];
            const float2 ww = ((const float2*)C.w0)[sidx[e] * 256 + o];
            wx = fmaf(g, ww.x, wx);
            wy = fmaf(g, ww.y, wy);
            bb = fmaf(g, C.b0[sidx[e] * 256 + o], bb);
        }
        unsigned short wxh = f2bf_rne(wx), wyh = f2bf_rne(wy), bh = f2bf_rne(bb);
        unsigned short wxl = f2bf_rne(wx - bf2f(wxh));
        unsigned short wyl = f2bf_rne(wy - bf2f(wyh));
        unsigned short bl  = f2bf_rne(bb - bf2f(bh));
        const int wv = o >> 6, ntl = (o >> 4) & 3, colo = o & 15;
        short8 frag = { (short)wxh, (short)wyh, (short)bh, (short)wxl,
                        (short)wyl, (short)bl,  (short)wxh, (short)wyh };
        short8 zero = { 0, 0, 0, 0, 0, 0, 0, 0 };
        short8* dst = (short8*)C.W0F + n * 1024 + wv * 256 + ntl * 64 + colo;
        dst[0]  = frag;
        dst[16] = zero;
        dst[32] = zero;
        dst[48] = zero;
    } else if (b < 832) {
        // ---- dense-GEMM combine for layers 1..3 ----
        const int idx = b - 64;
        const int lz = idx >> 8;           // 0,1,2 -> layers 1,2,3
        const int o  = idx & 255;
        const float *w, *bias; unsigned short *Bh, *Bl; float* bc;
        int Ereal, Epad;
        if (lz == 0)      { w = C.w1; bias = C.b1; Bh = C.Bh1; Bl = C.Bl1; bc = C.bc1; Ereal = 16;  Epad = 64;  }
        else if (lz == 1) { w = C.w2; bias = C.b2; Bh = C.Bh2; Bl = C.Bl2; bc = C.bc2; Ereal = 64;  Epad = 64;  }
        else              { w = C.w3; bias = C.b3; Bh = C.Bh3; Bl = C.Bl3; bc = C.bc3; Ereal = 256; Epad = 256; }
        const float* G = C.gdense + ((size_t)(lz + 1) * 64) * 1024;
        const int k = t;

        float acc[64];
        #pragma unroll
        for (int n = 0; n < 64; ++n) acc[n] = 0.f;

        for (int e0 = 0; e0 < Epad; e0 += 64) {
            __syncthreads();
            #pragma unroll
            for (int i = 0; i < 4; ++i) {
                const int flat = i * 1024 + t * 4;
                const int n = flat >> 6, eo = flat & 63;
                *(float4*)&Gs[n][eo] = *(const float4*)&G[(size_t)n * 1024 + e0 + eo];
            }
            __syncthreads();

            const float* wp = w + (size_t)o * 256 + k;
            float wv[4];
            #pragma unroll
            for (int q = 0; q < 4; ++q) {
                const int e = e0 + q;
                const int es = (e < Ereal) ? e : 0;
                wv[q] = wp[(size_t)es * 65536];
            }
            for (int ee = 0; ee < 64; ee += 4) {
                float wc[4];
                #pragma unroll
                for (int q = 0; q < 4; ++q) wc[q] = wv[q];
                if (ee < 60) {
                    #pragma unroll
                    for (int q = 0; q < 4; ++q) {
                        const int e = e0 + ee + 4 + q;
                        const int es = (e < Ereal) ? e : 0;
                        wv[q] = wp[(size_t)es * 65536];
                    }
                }
                #pragma unroll
                for (int n = 0; n < 64; ++n) {
                    const float4 g = *(const float4*)&Gs[n][ee];
                    acc[n] = fmaf(g.x, wc[0], acc[n]);
                    acc[n] = fmaf(g.y, wc[1], acc[n]);
                    acc[n] = fmaf(g.z, wc[2], acc[n]);
                    acc[n] = fmaf(g.w, wc[3], acc[n]);
                }
            }
        }

        // write split bf16 planes at B-fragment layout
        const int kap = kappa(k);
        const int kc = kap >> 5, qk = (kap >> 3) & 3, j = kap & 7;
        const int nt = o >> 4, colo = o & 15;
        const int base = (((kc * 16 + nt) << 6) + (qk << 4) + colo) * 8 + j;
        #pragma unroll 8
        for (int n = 0; n < 64; ++n) {
            unsigned short h = f2bf_rne(acc[n]);
            Bh[(size_t)n * 65536 + base] = h;
            Bl[(size_t)n * 65536 + base] = f2bf_rne(acc[n] - bf2f(h));
        }

        // bias for this o (threads 0..63 = instances), via compact lists
        if (t < 64) {
            const int n = t;
            const int l = lz + 1;
            const int K = (lz == 0) ? 4 : 32;
            float a2 = 0.f;
            for (int e = 0; e < K; ++e) {
                const int   ei = C.idxl[(l * 64 + n) * 256 + e];
                const float gv = C.vall[(l * 64 + n) * 256 + e];
                a2 = fmaf(gv, bias[ei * 256 + o], a2);
            }
            bc[n * 256 + o] = a2;
        }
    } else {
        // ---- layer-4 B-frag combine ----
        const int n = b - 832;
        sidx[t] = C.idxl[(4 * 64 + n) * 256 + t];
        sval[t] = C.vall[(4 * 64 + n) * 256 + t];
        __syncthreads();
        float a0 = 0.f, a1 = 0.f, a2 = 0.f;
        for (int e = 0; e < 256; ++e) {
            const float g = sval[e];
            const long base = (long)sidx[e] * 3 * 256 + t;
            a0 = fmaf(g, C.w4[base + 0],   a0);
            a1 = fmaf(g, C.w4[base + 256], a1);
            a2 = fmaf(g, C.w4[base + 512], a2);
        }
        const int kap = kappa(t);
        const int kc = kap >> 5, qk = (kap >> 3) & 3, j = kap & 7;
        unsigned short* Bhn = C.Bh4 + n * 4096;
        unsigned short* Bln = C.Bl4 + n * 4096;
        float av[3] = { a0, a1, a2 };
        #pragma unroll
        for (int o = 0; o < 3; ++o) {
            const int flat = ((kc << 6) + (qk << 4) + o) * 8 + j;
            unsigned short h = f2bf_rne(av[o]);
            Bhn[flat] = h;
            Bln[flat] = f2bf_rne(av[o] - bf2f(h));
        }
        if (t < 3) {
            float s = 0.f;
            for (int e = 0; e < 256; ++e)
                s = fmaf(sval[e], C.b4[sidx[e] * 3 + t], s);
            C.bc4[n * 3 + t] = s;
        }
    }
}

// ---------------------------------------------------------------------------
// Kernel 3: fused 5-layer MLP. Split-bf16 A planes in LDS. MFMA inner loop is
// 3 term-passes (hh / hl / lh) per kc so consecutive MFMAs never share an
// accumulator (reuse distance 16 >> MFMA latency).
// ---------------------------------------------------------------------------
struct FusedParams {
    const float* coords;
    const unsigned short* W0F;
    const unsigned short *Bh1, *Bl1; const float* bc1;
    const unsigned short *Bh2, *Bl2; const float* bc2;
    const unsigned short *Bh3, *Bl3; const float* bc3;
    const unsigned short *Bh4, *Bl4; const float* bc4;
    float* out;
};

__device__ __forceinline__ void epilogue_store(
        unsigned short (*PL)[16384], const f32x4 (*acc)[4], const float* bo30,
        int w, int lane) {
    const int quad = lane >> 4, col = lane & 15;
    const int qk  = (col >> 1) & 3;
    const int kcW = (w << 1) | (col & 1);
    const int j0  = (col >> 3) << 2;
    const int gb  = (kcW * 256 + (qk << 4) + (quad << 2)) * 8 + j0;
    unsigned short* wp0 = &PL[0][gb];
    unsigned short* wp1 = &PL[1][gb];
    #pragma unroll
    for (int mt = 0; mt < 4; ++mt) {
        #pragma unroll
        for (int r = 0; r < 4; ++r) {
            unsigned u[4], v[4];
            #pragma unroll
            for (int ntl = 0; ntl < 4; ++ntl) {
                float x = __sinf(fmaf(acc[ntl][mt][r], 30.f, bo30[ntl]));
                unsigned ux = __float_as_uint(x);
                u[ntl] = ux;
                float rres = x - __uint_as_float(ux & 0xffff0000u);
                v[ntl] = rne_hi(__float_as_uint(rres));
            }
            uint2 hp, lp;
            hp.x = pack_hi16(u[0], u[1]); hp.y = pack_hi16(u[2], u[3]);
            lp.x = pack_hi16(v[0], v[1]); lp.y = pack_hi16(v[2], v[3]);
            const int offs = (mt * 64 + (r ^ qk)) * 8;
            *(uint2*)(wp0 + offs) = hp;
            *(uint2*)(wp1 + offs) = lp;
        }
    }
}

__device__ __forceinline__ void hidden_layer(
        unsigned short (*PL)[16384],
        const short8* __restrict__ Bh, const short8* __restrict__ Bl,
        const float* __restrict__ bc, int w, int lane, int lanep) {
    const int col = lane & 15;
    f32x4 acc[4][4];
    #pragma unroll
    for (int a = 0; a < 4; ++a)
        #pragma unroll
        for (int m = 0; m < 4; ++m) acc[a][m] = (f32x4){0.f, 0.f, 0.f, 0.f};

    const short8* a0 = (const short8*)&PL[0][lanep * 8];
    const short8* a1 = (const short8*)&PL[1][lanep * 8];
    const short8* bph = Bh + (w << 8) + lane;
    const short8* bpl = Bl + (w << 8) + lane;

    short8 pbh[2][4], pbl[2][4];
    #pragma unroll
    for (int ntl = 0; ntl < 4; ++ntl) {
        pbh[0][ntl] = bph[ntl << 6];
        pbl[0][ntl] = bpl[ntl << 6];
    }
    #pragma unroll
    for (int kc = 0; kc < 8; ++kc) {
        const int cur = kc & 1;
        if (kc < 7) {
            #pragma unroll
            for (int ntl = 0; ntl < 4; ++ntl) {
                pbh[cur ^ 1][ntl] = bph[(kc + 1) * 1024 + (ntl << 6)];
                pbl[cur ^ 1][ntl] = bpl[(kc + 1) * 1024 + (ntl << 6)];
            }
        }
        short8 Ah[4], Al[4];
        #pragma unroll
        for (int mt = 0; mt < 4; ++mt) {
            Ah[mt] = a0[(kc * 4 + mt) << 6];
            Al[mt] = a1[(kc * 4 + mt) << 6];
        }
        // pass 1: Ah x Bh  (16 independent accumulators)
        #pragma unroll
        for (int ntl = 0; ntl < 4; ++ntl)
            #pragma unroll
            for (int mt = 0; mt < 4; ++mt)
                acc[ntl][mt] = MFMA16(Ah[mt], pbh[cur][ntl], acc[ntl][mt]);
        // pass 2: Ah x Bl
        #pragma unroll
        for (int ntl = 0; ntl < 4; ++ntl)
            #pragma unroll
            for (int mt = 0; mt < 4; ++mt)
                acc[ntl][mt] = MFMA16(Ah[mt], pbl[cur][ntl], acc[ntl][mt]);
        // pass 3: Al x Bh
        #pragma unroll
        for (int ntl = 0; ntl < 4; ++ntl)
            #pragma unroll
            for (int mt = 0; mt < 4; ++mt)
                acc[ntl][mt] = MFMA16(Al[mt], pbh[cur][ntl], acc[ntl][mt]);
    }
    __syncthreads();

    float bo30[4];
    #pragma unroll
    for (int ntl = 0; ntl < 4; ++ntl)
        bo30[ntl] = 30.f * bc[(w << 6) + (ntl << 4) + col];
    epilogue_store(PL, acc, bo30, w, lane);
    __syncthreads();
}

__global__ __launch_bounds__(256, 2) void fused_mlp(FusedParams P) {
    __shared__ __align__(16) unsigned short PL[2][16384];
    const int bid = blockIdx.x;
    // XCD-aware swizzle: all 128 tiles of an instance land on one XCD
    const int c = bid & 7, jj = bid >> 3;
    const int n = c * 8 + (jj >> 7);
    const int p0g = (jj & 127) * 64;
    const int t = threadIdx.x;
    const int lane = t & 63, w = t >> 6;
    const int quad = lane >> 4, col = lane & 15;
    const int lanep = lane ^ ((lane >> 4) & 3);

    // ---- layer 0 via MFMA ----
    {
        short8 A0[4];
        if (quad == 0) {
            #pragma unroll
            for (int mt = 0; mt < 4; ++mt) {
                const float2 cc = ((const float2*)P.coords)[n * N_PTS + p0g + mt * 16 + col];
                unsigned ux = __float_as_uint(cc.x), uy = __float_as_uint(cc.y);
                unsigned xh = ux & 0xffff0000u, yh = uy & 0xffff0000u;
                unsigned short xl = f2bf_rne(cc.x - __uint_as_float(xh));
                unsigned short yl = f2bf_rne(cc.y - __uint_as_float(yh));
                short8 a = { (short)(xh >> 16), (short)(yh >> 16), (short)0x3f80,
                             (short)(xh >> 16), (short)(yh >> 16), (short)0x3f80,
                             (short)xl, (short)yl };
                A0[mt] = a;
            }
        } else {
            short8 z = { 0, 0, 0, 0, 0, 0, 0, 0 };
            #pragma unroll
            for (int mt = 0; mt < 4; ++mt) A0[mt] = z;
        }
        f32x4 acc[4][4];
        const short8* b0p = (const short8*)P.W0F + n * 1024 + w * 256 + lane;
        #pragma unroll
        for (int ntl = 0; ntl < 4; ++ntl) {
            const short8 b0 = b0p[ntl << 6];
            #pragma unroll
            for (int mt = 0; mt < 4; ++mt) {
                f32x4 z = (f32x4){0.f, 0.f, 0.f, 0.f};
                acc[ntl][mt] = MFMA16(A0[mt], b0, z);
            }
        }
        const float bz[4] = { 0.f, 0.f, 0.f, 0.f };
        epilogue_store(PL, acc, bz, w, lane);
    }
    __syncthreads();

    // ---- hidden layers 1..3 ----
    hidden_layer(PL, (const short8*)P.Bh1 + (size_t)n * 8192,
                     (const short8*)P.Bl1 + (size_t)n * 8192,
                     P.bc1 + n * 256, w, lane, lanep);
    hidden_layer(PL, (const short8*)P.Bh2 + (size_t)n * 8192,
                     (const short8*)P.Bl2 + (size_t)n * 8192,
                     P.bc2 + n * 256, w, lane, lanep);
    hidden_layer(PL, (const short8*)P.Bh3 + (size_t)n * 8192,
                     (const short8*)P.Bl3 + (size_t)n * 8192,
                     P.bc3 + n * 256, w, lane, lanep);

    // ---- layer 4: 256 -> 3 via MFMA; wave w handles p-tile mt=w ----
    {
        const short8* B4h = (const short8*)P.Bh4 + (n << 9);
        const short8* B4l = (const short8*)P.Bl4 + (n << 9);
        const short8* a0 = (const short8*)&PL[0][lanep * 8];
        const short8* a1 = (const short8*)&PL[1][lanep * 8];
        f32x4 acc4 = (f32x4){0.f, 0.f, 0.f, 0.f};
        #pragma unroll
        for (int kc = 0; kc < 8; ++kc) {
            short8 ah = a0[(kc * 4 + w) << 6];
            short8 al = a1[(kc * 4 + w) << 6];
            short8 bh = B4h[kc * 64 + lane];
            short8 bl = B4l[kc * 64 + lane];
            acc4 = MFMA16(ah, bh, acc4);
            acc4 = MFMA16(ah, bl, acc4);
            acc4 = MFMA16(al, bh, acc4);
        }
        if (col < 3) {
            const float bo = P.bc4[n * 3 + col];
            #pragma unroll
            for (int r = 0; r < 4; ++r) {
                const int p = (w << 4) + (quad << 2) + r;
                P.out[((long)(n * N_PTS + p0g + p)) * 3 + col] = acc4[r] + bo;
            }
        }
    }
}

// ---------------------------------------------------------------------------
extern "C" void kernel_launch(void* const* d_in, const int* in_sizes, int n_in,
                              void* d_out, int out_size, void* d_ws, size_t ws_size,
                              hipStream_t stream) {
    const float* latents = (const float*)d_in[0];
    const float* coords  = (const float*)d_in[1];
    const float* gw[5] = { (const float*)d_in[2], (const float*)d_in[4],
                           (const float*)d_in[6], (const float*)d_in[8],
                           (const float*)d_in[10] };
    const float* gb[5] = { (const float*)d_in[3], (const float*)d_in[5],
                           (const float*)d_in[7], (const float*)d_in[9],
                           (const float*)d_in[11] };
    const float* w[5]  = { (const float*)d_in[12], (const float*)d_in[14],
                           (const float*)d_in[16], (const float*)d_in[18],
                           (const float*)d_in[20] };
    const float* b[5]  = { (const float*)d_in[13], (const float*)d_in[15],
                           (const float*)d_in[17], (const float*)d_in[19],
                           (const float*)d_in[21] };

    char* ws = (char*)d_ws;
    size_t off = 0;
    auto alloc = [&](size_t bytes) { char* p = ws + off; off += (bytes + 255) & ~(size_t)255; return p; };
    int*   idxl   = (int*)  alloc(5 * 64 * 256 * 4);
    float* vall   = (float*)alloc(5 * 64 * 256 * 4);
    float* gdense = (float*)alloc((size_t)5 * 64 * 1024 * 4);
    float* bc1  = (float*)alloc((size_t)64 * 256 * 4);
    float* bc2  = (float*)alloc((size_t)64 * 256 * 4);
    float* bc3  = (float*)alloc((size_t)64 * 256 * 4);
    float* bc4  = (float*)alloc((size_t)64 * 3 * 4);
    unsigned short* W0F = (unsigned short*)alloc((size_t)64 * 8192 * 2);
    const size_t PLANE = (size_t)64 * 65536 * 2;
    unsigned short* Bh1 = (unsigned short*)alloc(PLANE);
    unsigned short* Bl1 = (unsigned short*)alloc(PLANE);
    unsigned short* Bh2 = (unsigned short*)alloc(PLANE);
    unsigned short* Bl2 = (unsigned short*)alloc(PLANE);
    unsigned short* Bh3 = (unsigned short*)alloc(PLANE);
    unsigned short* Bl3 = (unsigned short*)alloc(PLANE);
    unsigned short* Bh4 = (unsigned short*)alloc((size_t)64 * 4096 * 2);
    unsigned short* Bl4 = (unsigned short*)alloc((size_t)64 * 4096 * 2);

    // 1) gate + top-k (compact + dense)
    GateParams gp;
    gp.latents = latents;
    for (int l = 0; l < 5; ++l) { gp.gw[l] = gw[l]; gp.gb[l] = gb[l]; }
    gp.idx_out = idxl; gp.val_out = vall; gp.gdense = gdense;
    gp.E[0]=8; gp.E[1]=16; gp.E[2]=64; gp.E[3]=256; gp.E[4]=1024;
    gp.K[0]=4; gp.K[1]=4;  gp.K[2]=32; gp.K[3]=32;  gp.K[4]=256;
    hipLaunchKernelGGL(gate_topk, dim3(64, 5), dim3(256), 0, stream, gp);

    // 2) all combines in one launch (dense-GEMM for hidden layers)
    CombParams cp;
    cp.w0 = w[0]; cp.b0 = b[0]; cp.w1 = w[1]; cp.b1 = b[1];
    cp.w2 = w[2]; cp.b2 = b[2]; cp.w3 = w[3]; cp.b3 = b[3];
    cp.w4 = w[4]; cp.b4 = b[4];
    cp.idxl = idxl; cp.vall = vall; cp.gdense = gdense;
    cp.W0F = W0F;
    cp.Bh1 = Bh1; cp.Bl1 = Bl1; cp.Bh2 = Bh2; cp.Bl2 = Bl2;
    cp.Bh3 = Bh3; cp.Bl3 = Bl3; cp.Bh4 = Bh4; cp.Bl4 = Bl4;
    cp.bc1 = bc1; cp.bc2 = bc2; cp.bc3 = bc3; cp.bc4 = bc4;
    hipLaunchKernelGGL(combine_all, dim3(896), dim3(256), 0, stream, cp);

    // 3) fused 5-layer MLP
    FusedParams fp;
    fp.coords = coords;
    fp.W0F = W0F;
    fp.Bh1 = Bh1; fp.Bl1 = Bl1; fp.bc1 = bc1;
    fp.Bh2 = Bh2; fp.Bl2 = Bl2; fp.bc2 = bc2;
    fp.Bh3 = Bh3; fp.Bl3 = Bl3; fp.bc3 = bc3;
    fp.Bh4 = Bh4; fp.Bl4 = Bl4; fp.bc4 = bc4;
    fp.out = (float*)d_out;
    hipLaunchKernelGGL(fused_mlp, dim3(64 * 128), dim3(256), 0, stream, fp);
}